// Round 11
// baseline (95.716 us; speedup 1.0000x reference)
//
#include <hip/hip_runtime.h>
#include <hip/hip_bf16.h>
#include <math.h>

#define NTOK  16384
#define INF   2048
#define OUTF  2048
#define SR    45
#define RANK  8
#define BLK   64
#define NBLK  32
#define NRULE 256
#define NHIST 32
#define MAXSLOT (NTOK + NRULE * 15)   // 20224
#define NTILE32 (MAXSLOT / 32)        // 632 tiles of 32 slots

typedef __attribute__((ext_vector_type(8))) short bf16x8;
typedef __attribute__((ext_vector_type(4))) float f32x4;
typedef __attribute__((ext_vector_type(4))) short s16x4;

typedef const __attribute__((address_space(1))) unsigned int GU32;
typedef __attribute__((address_space(3))) unsigned int LU32;

#define MFMA __builtin_amdgcn_mfma_f32_16x16x32_bf16
#define SBAR() __builtin_amdgcn_sched_barrier(0)

// counted wait; sched_barrier after (rule #18: MFMA can hoist past asm waits)
#define VMCNT(n) do { asm volatile("s_waitcnt vmcnt(" #n ")" ::: "memory"); \
                      __builtin_amdgcn_sched_barrier(0); } while (0)
// raw barrier (no vmcnt(0) drain), pinned
#define BAR()    do { __builtin_amdgcn_sched_barrier(0); \
                      __builtin_amdgcn_s_barrier(); \
                      __builtin_amdgcn_sched_barrier(0); } while (0)
// un-sinkable 16B register load
#define GLOAD(dst, ptr) \
    asm volatile("global_load_dwordx4 %0, %1, off" : "=v"(dst) : "v"(ptr) : "memory")

__device__ inline short f2bs(float f) {
    __hip_bfloat16 h = __float2bfloat16(f);
    return *reinterpret_cast<short*>(&h);
}
__device__ inline bf16x8 cvt8(const float4& a, const float4& b) {
    bf16x8 r;
    r[0] = f2bs(a.x); r[1] = f2bs(a.y); r[2] = f2bs(a.z); r[3] = f2bs(a.w);
    r[4] = f2bs(b.x); r[5] = f2bs(b.y); r[6] = f2bs(b.z); r[7] = f2bs(b.w);
    return r;
}

// ---------------------------------------------------------------------------
// prep A: blocks 0..127 pack weights into MFMA B-frag layout (bf16);
//         blocks 128..159 per-block histogram slabs + init perm/srid.
// ---------------------------------------------------------------------------
__global__ void kprep_a(const int* __restrict__ rule_ids,
                        const float* __restrict__ shared_in,
                        const float* __restrict__ shared_out,
                        const float* __restrict__ rule_in,
                        const float* __restrict__ rule_out,
                        unsigned short* __restrict__ ssb,   // [64ch][2sub][3nf][64][8]
                        unsigned short* __restrict__ sob,   // [128CF][2kc][64][8]
                        unsigned short* __restrict__ rinf,  // [256][2half][64][8]
                        unsigned short* __restrict__ rof,   // [256][4cf][64][8]
                        int* __restrict__ ghist_part,
                        int* __restrict__ perm_p,
                        int* __restrict__ srid_p)
{
    if (blockIdx.x < 128) {
        const int tid = blockIdx.x * 256 + threadIdx.x;
        const int stride = 128 * 256;
        for (int idx = tid; idx < 64 * 3 * 512; idx += stride) {
            int ch = idx / 1536, rem = idx - ch * 1536;
            int nf = rem / 512;
            int l = (rem >> 3) & 63, j = idx & 7;
            int k = ch * 32 + ((l >> 4) << 3) + j;
            int col = nf * 16 + (l & 15);
            ssb[idx] = (col < SR) ? (unsigned short)f2bs(shared_in[(size_t)k * SR + col]) : 0;
        }
        for (int idx = tid; idx < 128 * 2 * 512; idx += stride) {
            int CF = idx >> 10;
            int kc = (idx >> 9) & 1;
            int l = (idx >> 3) & 63, j = idx & 7;
            int k = kc * 32 + ((l >> 4) << 3) + j;
            int col = CF * 16 + (l & 15);
            sob[idx] = (k < SR) ? (unsigned short)f2bs(shared_out[(size_t)k * OUTF + col]) : 0;
        }
        for (int idx = tid; idx < NRULE * 2 * 512; idx += stride) {
            int rid = idx >> 10;
            int half = (idx >> 9) & 1;
            int l = (idx >> 3) & 63, j = idx & 7;
            int r = l & 15;
            int s = half * 32 + ((l >> 4) << 3) + j;
            rinf[idx] = (r < RANK) ? (unsigned short)f2bs(rule_in[(size_t)rid * 512 + s * RANK + r]) : 0;
        }
        for (int idx = tid; idx < NRULE * 4 * 512; idx += stride) {
            int rid = idx >> 11;
            int cf = (idx >> 9) & 3;
            int l = (idx >> 3) & 63, j = idx & 7;
            int k = ((l >> 4) << 3) + j;
            int c = cf * 16 + (l & 15);
            rof[idx] = (k < RANK) ? (unsigned short)f2bs(rule_out[(size_t)rid * 512 + k * BLK + c]) : 0;
        }
    } else {
        __shared__ int lh[NRULE];
        const int tid = threadIdx.x;
        const int hb = blockIdx.x - 128;
        lh[tid] = 0;
        __syncthreads();
        const int base = hb * 512;
        atomicAdd(&lh[rule_ids[base + tid]], 1);
        atomicAdd(&lh[rule_ids[base + 256 + tid]], 1);
        __syncthreads();
        ghist_part[hb * NRULE + tid] = lh[tid];
        for (int j = tid; j < MAXSLOT / 32; j += 256) {
            int idx = hb * (MAXSLOT / 32) + j;
            perm_p[idx] = -1;
            srid_p[idx] = 0;
        }
    }
}

__global__ void kprep_scan(const int* __restrict__ ghist_part,
                           const float* __restrict__ logits,
                           int* __restrict__ gcnt,
                           int* __restrict__ srid_p,
                           float* __restrict__ sel_t,
                           int* __restrict__ ntot)
{
    __shared__ int sc[NRULE];
    const int tid = threadIdx.x;
    int h = 0;
#pragma unroll
    for (int b = 0; b < NHIST; ++b) h += ghist_part[b * NRULE + tid];
    const int pd = (h + 15) & ~15;
    sc[tid] = pd;
    for (int off = 1; off < NRULE; off <<= 1) {
        __syncthreads();
        int v = (tid >= off) ? sc[tid - off] : 0;
        __syncthreads();
        sc[tid] += v;
    }
    __syncthreads();
    const int excl = sc[tid] - pd;
    gcnt[tid] = excl;
    for (int q = h; q < pd; ++q) srid_p[excl + q] = tid;
    if (tid == NRULE - 1) *ntot = sc[tid];
    const float invT = 5.65685424949238f;
    const float* __restrict__ lg = logits + (size_t)tid * NBLK;
    float m = -1e30f;
    for (int b = 0; b < NBLK; ++b) m = fmaxf(m, lg[b] * invT);
    float s = 0.0f;
    for (int b = 0; b < NBLK; ++b) s += expf(lg[b] * invT - m);
    const float inv = 1.0f / s;
    for (int b = 0; b < NBLK; ++b)
        sel_t[(size_t)tid * NBLK + b] = expf(lg[b] * invT - m) * inv;
}

__global__ void kprep_scatter(const int* __restrict__ rule_ids,
                              int* __restrict__ gcnt,
                              int* __restrict__ perm_p,
                              int* __restrict__ srid_p)
{
    const int i = blockIdx.x * 256 + threadIdx.x;
    const int r = rule_ids[i];
    const int p = atomicAdd(&gcnt[r], 1);
    perm_p[p] = i;
    srid_p[p] = r;
}

// ---------------------------------------------------------------------------
// kmain: 32 slots, 256 thr = 4 waves = (strip s = w&1, parity par = w>>1).
// Phase 1: x DMA'd to LDS ring[3], RAW s_barrier + counted vmcnt (no drain);
//   wave (s,par) computes whole chunks of its parity (hidden wave-local);
//   weights via inline-asm register ring (un-sinkable), 2 chunks ahead.
// Phase 2: wave (s,p) covers 1024 cols; sob inline-asm ring depth 3,
//   counted vmcnt incl. stores; dummy-row stores keep the count exact.
// LDS 45 KB -> 3 blocks/CU.
// ---------------------------------------------------------------------------
__global__ __launch_bounds__(256, 3)
void kmain(const float* __restrict__ x,
           const int* __restrict__ perm_p,
           const int* __restrict__ srid_p,
           const unsigned short* __restrict__ ssb,
           const unsigned short* __restrict__ sob,
           const unsigned short* __restrict__ rinf,
           const unsigned short* __restrict__ rof,
           const float* __restrict__ sel_t,
           const int* __restrict__ ntot,
           float* __restrict__ dummy,
           float* __restrict__ out)
{
    __shared__ __align__(16) float xbuf[3][2048];               // 24 KB ring
    __shared__ __align__(16) unsigned short hs_lds[2][16][264]; // 16.9 KB
    __shared__ __align__(16) unsigned short t_bf[32][72];       // 4.6 KB

#define TRD(W, SL, C) (((float*)xbuf)[(((W) * 16 + (SL)) * 52) + (C)])

    const int slot0 = blockIdx.x * 32;
    if (slot0 >= *ntot) return;

    const int tid  = threadIdx.x;
    const int lane = tid & 63;
    const int w    = tid >> 6;            // 0..3
    const int s    = w & 1;               // strip
    const int par  = w >> 1;              // chunk parity (ph1) / col-half (ph2)
    const int row_l = lane & 15, grp = lane >> 4;
    const int slotbase = slot0 + s * 16;

    const int rid_u = __builtin_amdgcn_readfirstlane(srid_p[slotbase]);

    // ---- staging sources: thread stages rows r0 and r0+16, unit u ---------
    const int r0 = tid >> 4;
    const int u  = tid & 15;
    int tokA = perm_p[slot0 + r0];       if (tokA < 0) tokA = 0;
    int tokB = perm_p[slot0 + r0 + 16];  if (tokB < 0) tokB = 0;
    const char* gA = (const char*)(x + (size_t)tokA * INF) + ((u ^ (r0 & 7)) << 4);
    const char* gB = (const char*)(x + (size_t)tokB * INF) + (((u ^ ((r0 + 16) & 7))) << 4);

#define STAGE(CH) do { \
        char* _lb = (char*)xbuf + (size_t)((CH) % 3) * 8192 + (w << 10); \
        const size_t _o = (size_t)(CH) << 8; \
        __builtin_amdgcn_global_load_lds((GU32*)(gA + _o), (LU32*)_lb,          16, 0, 0); \
        __builtin_amdgcn_global_load_lds((GU32*)(gB + _o), (LU32*)(_lb + 4096), 16, 0, 0); \
    } while (0)

    // ds_read byte offsets inside one x buffer (sub q, element e)
    const int rphys = s * 16 + row_l;
#define XOFF(Q, E) ((rphys * 16 + ((((Q) * 8) + grp * 2 + (E)) ^ (row_l & 7))) << 4)
    const int off00 = XOFF(0, 0), off01 = XOFF(0, 1);
    const int off10 = XOFF(1, 0), off11 = XOFF(1, 1);

    const unsigned short* __restrict__ sbase = ssb + lane * 8;

    bf16x8 ri0, ri1;
    GLOAD(ri0, rinf + ((size_t)rid_u * 2 + 0) * 512 + lane * 8);
    GLOAD(ri1, rinf + ((size_t)rid_u * 2 + 1) * 512 + lane * 8);

    f32x4 aT0 = {0.f, 0.f, 0.f, 0.f};
    f32x4 aT1 = {0.f, 0.f, 0.f, 0.f};
    f32x4 aT2 = {0.f, 0.f, 0.f, 0.f};

    bf16x8 wreg[2][6];

#define WLOAD(SLOT, CH) do { \
        const unsigned short* _wp = sbase + (size_t)(CH) * 3072; \
        GLOAD(wreg[SLOT][0], _wp); \
        GLOAD(wreg[SLOT][1], _wp + 512); \
        GLOAD(wreg[SLOT][2], _wp + 1024); \
        GLOAD(wreg[SLOT][3], _wp + 1536); \
        GLOAD(wreg[SLOT][4], _wp + 2048); \
        GLOAD(wreg[SLOT][5], _wp + 2560); \
    } while (0)

    // prologue: D(0), D(1), W(par)  -> mimics steady-state issue log
    STAGE(0); STAGE(1);
    if (par == 0) WLOAD(0, 0); else WLOAD(0, 1);

#pragma unroll
    for (int ch = 0; ch < 32; ++ch) {
        if (ch < 30) STAGE(ch + 2);
        const bool mine = ((ch & 1) == par);
        // exact counted waits (issue-log-derived; see analysis)
        if (mine) { if (ch < 30) VMCNT(4);  else if (ch == 30) VMCNT(2); else VMCNT(0); }
        else      { if (ch < 30) VMCNT(10); else if (ch == 30) VMCNT(8); else VMCNT(0); }
        BAR();                             // all waves' D(ch) landed
        if (mine) {
            const int slot = (ch >> 1) & 1;
            const char* xb = (const char*)xbuf + (size_t)(ch % 3) * 8192;
            const float4 fa0 = *(const float4*)(xb + off00);
            const float4 fa1 = *(const float4*)(xb + off01);
            const float4 fb0 = *(const float4*)(xb + off10);
            const float4 fb1 = *(const float4*)(xb + off11);
            const bf16x8 af0 = cvt8(fa0, fa1);
            const bf16x8 af1 = cvt8(fb0, fb1);
            f32x4 aH = {0.f, 0.f, 0.f, 0.f};
            aT0 = MFMA(af0, wreg[slot][0], aT0, 0, 0, 0);
            aT1 = MFMA(af0, wreg[slot][1], aT1, 0, 0, 0);
            aT2 = MFMA(af0, wreg[slot][2], aT2, 0, 0, 0);
            aH  = MFMA(af0, ri0, aH, 0, 0, 0);
            aT0 = MFMA(af1, wreg[slot][3], aT0, 0, 0, 0);
            aT1 = MFMA(af1, wreg[slot][4], aT1, 0, 0, 0);
            aT2 = MFMA(af1, wreg[slot][5], aT2, 0, 0, 0);
            aH  = MFMA(af1, ri1, aH, 0, 0, 0);
            if (ch + 2 < 32) WLOAD(slot ^ 1, ch + 2);   // 2 chunks ahead
            const float sel = sel_t[(size_t)rid_u * NBLK + ch];
            if (row_l < RANK) {
#pragma unroll
                for (int q = 0; q < 4; ++q)
                    hs_lds[s][(grp << 2) + q][ch * 8 + row_l] =
                        (unsigned short)f2bs(aH[q] * sel);
            }
        }
        BAR();                             // readers done before slot reuse
    }

    // ---- t partials -> tred (xbuf reuse), reduce across parity ------------
#pragma unroll
    for (int q = 0; q < 4; ++q) {
        const int sl = (grp << 2) + q;
        TRD(w, sl, row_l)      = aT0[q];
        TRD(w, sl, 16 + row_l) = aT1[q];
        TRD(w, sl, 32 + row_l) = aT2[q];
    }
    __syncthreads();
    {
        const int sl = tid >> 3;           // 0..31
        const int st = sl >> 4, tk = sl & 15;
        const int cidx = tid & 7;
        if (cidx < 6) {
            const int c0 = cidx << 3;
            s16x4 v0, v1;
#pragma unroll
            for (int j = 0; j < 4; ++j) {
                v0[j] = f2bs(TRD(st, tk, c0 + j)     + TRD(st + 2, tk, c0 + j));
                v1[j] = f2bs(TRD(st, tk, c0 + 4 + j) + TRD(st + 2, tk, c0 + 4 + j));
            }
            *(s16x4*)(&t_bf[sl][c0])     = v0;
            *(s16x4*)(&t_bf[sl][c0 + 4]) = v1;
        } else {
            const int c0 = 48 + ((cidx - 6) << 3);
            const s16x4 z = {0, 0, 0, 0};
            *(s16x4*)(&t_bf[sl][c0])     = z;
            *(s16x4*)(&t_bf[sl][c0 + 4]) = z;
        }
    }
    __syncthreads();

    // ================= phase 2: out = t@shared_out + hs@rule_out ===========
    {
        const int p = par;                 // col-half: [p*1024, +1024)
        const bf16x8 at0 = *(const bf16x8*)(&t_bf[s * 16 + row_l][grp << 3]);
        const bf16x8 at1 = *(const bf16x8*)(&t_bf[s * 16 + row_l][32 + (grp << 3)]);

        bf16x8 rfv[4];
#pragma unroll
        for (int i = 0; i < 4; ++i)
            GLOAD(rfv[i], rof + ((size_t)rid_u * 4 + i) * 512 + lane * 8);

        const int4 pv = *(const int4*)(perm_p + slotbase + (grp << 2));
        float* const orow0 = (pv.x < 0) ? dummy : out + (size_t)pv.x * OUTF;
        float* const orow1 = (pv.y < 0) ? dummy : out + (size_t)pv.y * OUTF;
        float* const orow2 = (pv.z < 0) ? dummy : out + (size_t)pv.z * OUTF;
        float* const orow3 = (pv.w < 0) ? dummy : out + (size_t)pv.w * OUTF;

        const int CF0 = p * 64;
        const int bb0 = p * 16;
        const unsigned short* __restrict__ sobw = sob + (size_t)CF0 * 1024 + lane * 8;

        bf16x8 sb[4][2];
        bf16x8 ah[2];
        const bf16x8 zz = {0, 0, 0, 0, 0, 0, 0, 0};

#define SLOADQ(SL, QI) do { \
        GLOAD(sb[SL][0], sobw + (size_t)(QI) * 1024); \
        GLOAD(sb[SL][1], sobw + (size_t)(QI) * 1024 + 512); \
    } while (0)
#define LOADA(SL, BI) do { \
        ah[SL] = zz; \
        if (lane < 16) \
            ah[SL] = *(const bf16x8*)(&hs_lds[s][lane][(bb0 + (BI)) * 8]); \
    } while (0)

        SLOADQ(0, 0); SLOADQ(1, 1); SLOADQ(2, 2);
        LOADA(0, 0);

#pragma unroll
        for (int qi = 0; qi < 64; ++qi) {
            if (qi < 61) SLOADQ((qi + 3) & 3, qi + 3);
            if ((qi & 3) == 0 && qi < 60) LOADA(((qi >> 2) + 1) & 1, (qi >> 2) + 1);
            // exact counted waits (loads 2/qi + stores 4/qi in the log)
            if (qi == 0)       VMCNT(6);
            else if (qi == 1)  VMCNT(10);
            else if (qi == 2)  VMCNT(14);
            else if (qi <= 60) VMCNT(18);
            else if (qi == 61) VMCNT(16);
            else if (qi == 62) VMCNT(14);
            else               VMCNT(12);
            f32x4 acc = {0.f, 0.f, 0.f, 0.f};
            acc = MFMA(at0, sb[qi & 3][0], acc, 0, 0, 0);
            acc = MFMA(at1, sb[qi & 3][1], acc, 0, 0, 0);
            acc = MFMA(ah[(qi >> 2) & 1], rfv[qi & 3], acc, 0, 0, 0);
            const int col = ((CF0 + qi) << 4) + row_l;
            orow0[col] = acc[0];
            orow1[col] = acc[1];
            orow2[col] = acc[2];
            orow3[col] = acc[3];
        }
#undef SLOADQ
#undef LOADA
    }
}

extern "C" void kernel_launch(void* const* d_in, const int* in_sizes, int n_in,
                              void* d_out, int out_size, void* d_ws, size_t ws_size,
                              hipStream_t stream)
{
    const float* x          = (const float*)d_in[0];
    const int*   rule_ids   = (const int*)  d_in[1];
    const float* shared_in  = (const float*)d_in[2];
    const float* shared_out = (const float*)d_in[3];
    const float* rule_in    = (const float*)d_in[4];
    const float* rule_out   = (const float*)d_in[5];
    const float* logits     = (const float*)d_in[6];
    float* out = (float*)d_out;

    char* p = (char*)d_ws;
    auto carve = [&p](size_t bytes) {
        char* r = p;
        p += (bytes + 255) & ~(size_t)255;
        return r;
    };
    int*            perm_p = (int*)carve(MAXSLOT * 4);
    int*            srid_p = (int*)carve(MAXSLOT * 4);
    unsigned short* ssb    = (unsigned short*)carve(64 * 3 * 512 * 2);
    unsigned short* sob    = (unsigned short*)carve(128 * 2 * 512 * 2);
    unsigned short* rinf   = (unsigned short*)carve((size_t)NRULE * 2 * 512 * 2);
    unsigned short* rof    = (unsigned short*)carve((size_t)NRULE * 4 * 512 * 2);
    float*          sel_t  = (float*)carve((size_t)NRULE * NBLK * 4);
    int*            ghistp = (int*)carve((size_t)NHIST * NRULE * 4);
    int*            gcnt   = (int*)carve(NRULE * 4);
    int*            ntot   = (int*)carve(4);
    float*          dummy  = (float*)carve((size_t)OUTF * 4);

    kprep_a<<<dim3(160), dim3(256), 0, stream>>>(
        rule_ids, shared_in, shared_out, rule_in, rule_out,
        ssb, sob, rinf, rof, ghistp, perm_p, srid_p);
    kprep_scan<<<dim3(1), dim3(256), 0, stream>>>(
        ghistp, logits, gcnt, srid_p, sel_t, ntot);
    kprep_scatter<<<dim3(64), dim3(256), 0, stream>>>(
        rule_ids, gcnt, perm_p, srid_p);
    kmain<<<dim3(NTILE32), dim3(256), 0, stream>>>(
        x, perm_p, srid_p, ssb, sob, rinf, rof, sel_t, ntot, dummy, out);
}

// Round 12
// 88.800 us; speedup vs baseline: 1.0779x; 1.0779x over previous
//
#include <hip/hip_runtime.h>
#include <hip/hip_bf16.h>
#include <math.h>

#define NTOK  16384
#define INF   2048
#define OUTF  2048
#define SR    45
#define RANK  8
#define BLK   64
#define NBLK  32
#define NRULE 256
#define NHIST 32
#define MAXSLOT (NTOK + NRULE * 15)   // 20224
#define NTILE16 (MAXSLOT / 16)        // 1264 tiles of 16 slots

typedef __attribute__((ext_vector_type(8))) short bf16x8;
typedef __attribute__((ext_vector_type(4))) float f32x4;
typedef __attribute__((ext_vector_type(4))) short s16x4;

typedef const __attribute__((address_space(1))) unsigned int GU32;
typedef __attribute__((address_space(3))) unsigned int LU32;

#define MFMA __builtin_amdgcn_mfma_f32_16x16x32_bf16
#define SBAR() __builtin_amdgcn_sched_barrier(0)

__device__ inline short f2bs(float f) {
    __hip_bfloat16 h = __float2bfloat16(f);
    return *reinterpret_cast<short*>(&h);
}
__device__ inline bf16x8 cvt8(const float4& a, const float4& b) {
    bf16x8 r;
    r[0] = f2bs(a.x); r[1] = f2bs(a.y); r[2] = f2bs(a.z); r[3] = f2bs(a.w);
    r[4] = f2bs(b.x); r[5] = f2bs(b.y); r[6] = f2bs(b.z); r[7] = f2bs(b.w);
    return r;
}

// ---------------------------------------------------------------------------
// prep A: blocks 0..127 pack weights into MFMA B-frag layout (bf16);
//         blocks 128..159 per-block histogram slabs + init perm/srid.
// ---------------------------------------------------------------------------
__global__ void kprep_a(const int* __restrict__ rule_ids,
                        const float* __restrict__ shared_in,
                        const float* __restrict__ shared_out,
                        const float* __restrict__ rule_in,
                        const float* __restrict__ rule_out,
                        unsigned short* __restrict__ ssb,   // [64k32][3nf][64][8]
                        unsigned short* __restrict__ sob,   // [128CF][2kc][64][8]
                        unsigned short* __restrict__ rinf,  // [256][2half][64][8]
                        unsigned short* __restrict__ rof,   // [256][4cf][64][8]
                        int* __restrict__ ghist_part,
                        int* __restrict__ perm_p,
                        int* __restrict__ srid_p)
{
    if (blockIdx.x < 128) {
        const int tid = blockIdx.x * 256 + threadIdx.x;
        const int stride = 128 * 256;
        for (int idx = tid; idx < 64 * 3 * 512; idx += stride) {
            int ch = idx / 1536, rem = idx - ch * 1536;
            int nf = rem / 512;
            int l = (rem >> 3) & 63, j = idx & 7;
            int k = ch * 32 + ((l >> 4) << 3) + j;
            int col = nf * 16 + (l & 15);
            ssb[idx] = (col < SR) ? (unsigned short)f2bs(shared_in[(size_t)k * SR + col]) : 0;
        }
        for (int idx = tid; idx < 128 * 2 * 512; idx += stride) {
            int CF = idx >> 10;
            int kc = (idx >> 9) & 1;
            int l = (idx >> 3) & 63, j = idx & 7;
            int k = kc * 32 + ((l >> 4) << 3) + j;
            int col = CF * 16 + (l & 15);
            sob[idx] = (k < SR) ? (unsigned short)f2bs(shared_out[(size_t)k * OUTF + col]) : 0;
        }
        for (int idx = tid; idx < NRULE * 2 * 512; idx += stride) {
            int rid = idx >> 10;
            int half = (idx >> 9) & 1;
            int l = (idx >> 3) & 63, j = idx & 7;
            int r = l & 15;
            int s = half * 32 + ((l >> 4) << 3) + j;
            rinf[idx] = (r < RANK) ? (unsigned short)f2bs(rule_in[(size_t)rid * 512 + s * RANK + r]) : 0;
        }
        for (int idx = tid; idx < NRULE * 4 * 512; idx += stride) {
            int rid = idx >> 11;
            int cf = (idx >> 9) & 3;
            int l = (idx >> 3) & 63, j = idx & 7;
            int k = ((l >> 4) << 3) + j;
            int c = cf * 16 + (l & 15);
            rof[idx] = (k < RANK) ? (unsigned short)f2bs(rule_out[(size_t)rid * 512 + k * BLK + c]) : 0;
        }
    } else {
        __shared__ int lh[NRULE];
        const int tid = threadIdx.x;
        const int hb = blockIdx.x - 128;
        lh[tid] = 0;
        __syncthreads();
        const int base = hb * 512;
        atomicAdd(&lh[rule_ids[base + tid]], 1);
        atomicAdd(&lh[rule_ids[base + 256 + tid]], 1);
        __syncthreads();
        ghist_part[hb * NRULE + tid] = lh[tid];
        for (int j = tid; j < MAXSLOT / 32; j += 256) {
            int idx = hb * (MAXSLOT / 32) + j;
            perm_p[idx] = -1;
            srid_p[idx] = 0;
        }
    }
}

__global__ void kprep_scan(const int* __restrict__ ghist_part,
                           const float* __restrict__ logits,
                           int* __restrict__ gcnt,
                           int* __restrict__ srid_p,
                           float* __restrict__ sel_t,
                           int* __restrict__ ntot)
{
    __shared__ int sc[NRULE];
    const int tid = threadIdx.x;
    int h = 0;
#pragma unroll
    for (int b = 0; b < NHIST; ++b) h += ghist_part[b * NRULE + tid];
    const int pd = (h + 15) & ~15;
    sc[tid] = pd;
    for (int off = 1; off < NRULE; off <<= 1) {
        __syncthreads();
        int v = (tid >= off) ? sc[tid - off] : 0;
        __syncthreads();
        sc[tid] += v;
    }
    __syncthreads();
    const int excl = sc[tid] - pd;
    gcnt[tid] = excl;
    for (int q = h; q < pd; ++q) srid_p[excl + q] = tid;
    if (tid == NRULE - 1) *ntot = sc[tid];
    const float invT = 5.65685424949238f;
    const float* __restrict__ lg = logits + (size_t)tid * NBLK;
    float m = -1e30f;
    for (int b = 0; b < NBLK; ++b) m = fmaxf(m, lg[b] * invT);
    float s = 0.0f;
    for (int b = 0; b < NBLK; ++b) s += expf(lg[b] * invT - m);
    const float inv = 1.0f / s;
    for (int b = 0; b < NBLK; ++b)
        sel_t[(size_t)tid * NBLK + b] = expf(lg[b] * invT - m) * inv;
}

__global__ void kprep_scatter(const int* __restrict__ rule_ids,
                              int* __restrict__ gcnt,
                              int* __restrict__ perm_p,
                              int* __restrict__ srid_p)
{
    const int i = blockIdx.x * 256 + threadIdx.x;
    const int r = rule_ids[i];
    const int p = atomicAdd(&gcnt[r], 1);
    perm_p[p] = i;
    srid_p[p] = r;
}

// ---------------------------------------------------------------------------
// kmain: 16 slots (one rule-uniform strip), 128 thr = 2 waves (kh = k-sub).
// R10 schedule at half block size: x DMA'd to LDS (double-buffered, ONE
// __syncthreads per 64-col chunk, XOR source swizzle); hidden partials via
// hstmp cross-wave; t reduced via xbuf overlay; phase-2 SBAR ring.
// LDS ~21 KB -> 7 blocks/CU; grid 1264 -> ~5 resident blocks/CU: the
// barrier drain of one block hides under other blocks' compute (TLP).
// ---------------------------------------------------------------------------
__global__ __launch_bounds__(128, 4)
void kmain(const float* __restrict__ x,
           const int* __restrict__ perm_p,
           const int* __restrict__ srid_p,
           const unsigned short* __restrict__ ssb,
           const unsigned short* __restrict__ sob,
           const unsigned short* __restrict__ rinf,
           const unsigned short* __restrict__ rof,
           const float* __restrict__ sel_t,
           const int* __restrict__ ntot,
           float* __restrict__ out)
{
    __shared__ __align__(16) float xbuf[2][1024];             // 8 KB (dbuf)
    __shared__ __align__(16) float hstmp[2][2][16][8];        // 2 KB
    __shared__ __align__(16) unsigned short hs_lds[16][264];  // 8.25 KB
    __shared__ __align__(16) unsigned short t_bf[16][72];     // 2.25 KB

#define TRD(W, SL, C) (((float*)xbuf)[((W) * 16 + (SL)) * 52 + (C)])

    const int slot0 = blockIdx.x * 16;
    if (slot0 >= *ntot) return;

    const int tid  = threadIdx.x;       // 0..127
    const int lane = tid & 63;
    const int kh   = tid >> 6;          // k-sub (ph1) / col-half (ph2)
    const int row_l = lane & 15, grp = lane >> 4;

    const int rid_u = __builtin_amdgcn_readfirstlane(srid_p[slot0]);

    // staging: 16 rows x 16 units(16B); thread covers rows r0 and r0+8
    const int r0 = tid >> 4;            // 0..7
    const int u  = tid & 15;
    int tokA = perm_p[slot0 + r0];      if (tokA < 0) tokA = 0;
    int tokB = perm_p[slot0 + r0 + 8];  if (tokB < 0) tokB = 0;
    // (r0+8)&7 == r0&7 -> same swizzle for both rows
    const char* gA = (const char*)(x + (size_t)tokA * INF) + ((u ^ (r0 & 7)) << 4);
    const char* gB = (const char*)(x + (size_t)tokB * INF) + ((u ^ (r0 & 7)) << 4);

#define STAGE(CH) do { \
        char* _lb = (char*)xbuf + (((CH) & 1) << 12) + (kh << 10); \
        const size_t _o = (size_t)(CH) << 8; \
        __builtin_amdgcn_global_load_lds((GU32*)(gA + _o), (LU32*)_lb,          16, 0, 0); \
        __builtin_amdgcn_global_load_lds((GU32*)(gB + _o), (LU32*)(_lb + 2048), 16, 0, 0); \
    } while (0)

    // ds_read offsets (XOR-swizzled) for this wave's fragment
    const int offA = (row_l * 16 + ((kh * 8 + grp * 2 + 0) ^ (row_l & 7))) << 4;
    const int offB = (row_l * 16 + ((kh * 8 + grp * 2 + 1) ^ (row_l & 7))) << 4;

    const bf16x8 ri = *(const bf16x8*)(rinf + ((size_t)rid_u * 2 + kh) * 512 + lane * 8);

    f32x4 aT0 = {0.f, 0.f, 0.f, 0.f};
    f32x4 aT1 = {0.f, 0.f, 0.f, 0.f};
    f32x4 aT2 = {0.f, 0.f, 0.f, 0.f};

    STAGE(0);
    __syncthreads();

    for (int ch = 0; ch < 32; ++ch) {
        if (ch < 31) STAGE(ch + 1);
        // finish hidden of previous chunk (hstmp written before last barrier)
        if (ch > 0) {
            const int b = ch - 1, pb = b & 1;
            const int sl = tid >> 3, r = tid & 7;
            const float v = hstmp[pb][0][sl][r] + hstmp[pb][1][sl][r];
            hs_lds[sl][b * 8 + r] =
                (unsigned short)f2bs(v * sel_t[(size_t)rid_u * NBLK + b]);
        }
        // compute sub kh of chunk ch
        {
            const char* xb = (const char*)xbuf + ((ch & 1) << 12);
            const float4 fa = *(const float4*)(xb + offA);
            const float4 fb = *(const float4*)(xb + offB);
            const bf16x8 af = cvt8(fa, fb);
            const unsigned short* sp = ssb + (size_t)(ch * 2 + kh) * 1536 + lane * 8;
            f32x4 aH = {0.f, 0.f, 0.f, 0.f};
            aT0 = MFMA(af, *(const bf16x8*)(sp),        aT0, 0, 0, 0);
            aT1 = MFMA(af, *(const bf16x8*)(sp + 512),  aT1, 0, 0, 0);
            aT2 = MFMA(af, *(const bf16x8*)(sp + 1024), aT2, 0, 0, 0);
            aH  = MFMA(af, ri, aH, 0, 0, 0);
            if (row_l < RANK) {
#pragma unroll
                for (int q = 0; q < 4; ++q)
                    hstmp[ch & 1][kh][(grp << 2) + q][row_l] = aH[q];
            }
        }
        __syncthreads();                 // DMA(ch+1) landed; hstmp[ch] visible
    }

    // ---- epilogue: hidden for chunk 31; t partials -> tred (xbuf overlay) --
    {
        const int b = 31, pb = 1;
        const int sl = tid >> 3, r = tid & 7;
        const float v = hstmp[pb][0][sl][r] + hstmp[pb][1][sl][r];
        hs_lds[sl][b * 8 + r] =
            (unsigned short)f2bs(v * sel_t[(size_t)rid_u * NBLK + b]);
    }
#pragma unroll
    for (int q = 0; q < 4; ++q) {
        const int sl = (grp << 2) + q;
        TRD(kh, sl, row_l)      = aT0[q];
        TRD(kh, sl, 16 + row_l) = aT1[q];
        TRD(kh, sl, 32 + row_l) = aT2[q];
    }
    __syncthreads();
    {   // reduce the 2 k-subs -> bf16 t (16 slots x 64 cols, K-padded)
        const int sl = tid >> 3;         // 0..15
        const int cidx = tid & 7;
        if (cidx < 6) {
            const int c0 = cidx << 3;
            s16x4 v0, v1;
#pragma unroll
            for (int j = 0; j < 4; ++j) {
                v0[j] = f2bs(TRD(0, sl, c0 + j)     + TRD(1, sl, c0 + j));
                v1[j] = f2bs(TRD(0, sl, c0 + 4 + j) + TRD(1, sl, c0 + 4 + j));
            }
            *(s16x4*)(&t_bf[sl][c0])     = v0;
            *(s16x4*)(&t_bf[sl][c0 + 4]) = v1;
        } else {
            const int c0 = 48 + ((cidx - 6) << 3);
            const s16x4 z = {0, 0, 0, 0};
            *(s16x4*)(&t_bf[sl][c0])     = z;
            *(s16x4*)(&t_bf[sl][c0 + 4]) = z;
        }
    }
    __syncthreads();

    // ================= phase 2: out = t@shared_out + hs@rule_out ===========
    {
        const int p = kh;                // col-half: [p*1024, +1024)
        const bf16x8 at0 = *(const bf16x8*)(&t_bf[row_l][grp << 3]);
        const bf16x8 at1 = *(const bf16x8*)(&t_bf[row_l][32 + (grp << 3)]);

        bf16x8 rfv[4];
#pragma unroll
        for (int i = 0; i < 4; ++i)
            rfv[i] = *(const bf16x8*)(rof + ((size_t)rid_u * 4 + i) * 512 + lane * 8);

        const int4 pv = *(const int4*)(perm_p + slot0 + (grp << 2));
        float* const orow0 = out + (size_t)(pv.x < 0 ? 0 : pv.x) * OUTF;
        float* const orow1 = out + (size_t)(pv.y < 0 ? 0 : pv.y) * OUTF;
        float* const orow2 = out + (size_t)(pv.z < 0 ? 0 : pv.z) * OUTF;
        float* const orow3 = out + (size_t)(pv.w < 0 ? 0 : pv.w) * OUTF;

        const int CF0 = p * 64;
        const int bb0 = p * 16;
        const unsigned short* __restrict__ sobw = sob + (size_t)CF0 * 1024 + lane * 8;

        bf16x8 sb[4][2];
        bf16x8 ah[2];
        const bf16x8 zz = {0, 0, 0, 0, 0, 0, 0, 0};

#define LOADQ(SL, QI) do { \
        const unsigned short* _sp = sobw + (size_t)(QI) * 1024; \
        sb[SL][0] = *(const bf16x8*)(_sp); \
        sb[SL][1] = *(const bf16x8*)(_sp + 512); \
    } while (0)
#define LOADA(SL, BI) do { \
        ah[SL] = zz; \
        if (lane < 16) \
            ah[SL] = *(const bf16x8*)(&hs_lds[lane][(bb0 + (BI)) * 8]); \
    } while (0)

        LOADQ(0, 0); LOADQ(1, 1); LOADQ(2, 2);
        LOADA(0, 0);
        SBAR();

#pragma unroll
        for (int qi = 0; qi < 64; ++qi) {
            if (qi < 61) LOADQ((qi + 3) & 3, qi + 3);
            if ((qi & 3) == 0 && qi < 60) LOADA(((qi >> 2) + 1) & 1, (qi >> 2) + 1);
            SBAR();
            f32x4 acc = {0.f, 0.f, 0.f, 0.f};
            acc = MFMA(at0, sb[qi & 3][0], acc, 0, 0, 0);
            acc = MFMA(at1, sb[qi & 3][1], acc, 0, 0, 0);
            acc = MFMA(ah[(qi >> 2) & 1], rfv[qi & 3], acc, 0, 0, 0);
            const int col = ((CF0 + qi) << 4) + row_l;
            if (pv.x >= 0) orow0[col] = acc[0];
            if (pv.y >= 0) orow1[col] = acc[1];
            if (pv.z >= 0) orow2[col] = acc[2];
            if (pv.w >= 0) orow3[col] = acc[3];
            SBAR();
        }
#undef LOADQ
#undef LOADA
    }
}

extern "C" void kernel_launch(void* const* d_in, const int* in_sizes, int n_in,
                              void* d_out, int out_size, void* d_ws, size_t ws_size,
                              hipStream_t stream)
{
    const float* x          = (const float*)d_in[0];
    const int*   rule_ids   = (const int*)  d_in[1];
    const float* shared_in  = (const float*)d_in[2];
    const float* shared_out = (const float*)d_in[3];
    const float* rule_in    = (const float*)d_in[4];
    const float* rule_out   = (const float*)d_in[5];
    const float* logits     = (const float*)d_in[6];
    float* out = (float*)d_out;

    char* p = (char*)d_ws;
    auto carve = [&p](size_t bytes) {
        char* r = p;
        p += (bytes + 255) & ~(size_t)255;
        return r;
    };
    int*            perm_p = (int*)carve(MAXSLOT * 4);
    int*            srid_p = (int*)carve(MAXSLOT * 4);
    unsigned short* ssb    = (unsigned short*)carve(64 * 3 * 512 * 2);
    unsigned short* sob    = (unsigned short*)carve(128 * 2 * 512 * 2);
    unsigned short* rinf   = (unsigned short*)carve((size_t)NRULE * 2 * 512 * 2);
    unsigned short* rof    = (unsigned short*)carve((size_t)NRULE * 4 * 512 * 2);
    float*          sel_t  = (float*)carve((size_t)NRULE * NBLK * 4);
    int*            ghistp = (int*)carve((size_t)NHIST * NRULE * 4);
    int*            gcnt   = (int*)carve(NRULE * 4);
    int*            ntot   = (int*)carve(4);

    kprep_a<<<dim3(160), dim3(256), 0, stream>>>(
        rule_ids, shared_in, shared_out, rule_in, rule_out,
        ssb, sob, rinf, rof, ghistp, perm_p, srid_p);
    kprep_scan<<<dim3(1), dim3(256), 0, stream>>>(
        ghistp, logits, gcnt, srid_p, sel_t, ntot);
    kprep_scatter<<<dim3(64), dim3(256), 0, stream>>>(
        rule_ids, gcnt, perm_p, srid_p);
    kmain<<<dim3(NTILE16), dim3(128), 0, stream>>>(
        x, perm_p, srid_p, ssb, sob, rinf, rof, sel_t, ntot, out);
}

// Round 13
// 88.768 us; speedup vs baseline: 1.0783x; 1.0004x over previous
//
#include <hip/hip_runtime.h>
#include <hip/hip_bf16.h>
#include <math.h>

#define NTOK  16384
#define INF   2048
#define OUTF  2048
#define SR    45
#define RANK  8
#define BLK   64
#define NBLK  32
#define NRULE 256
#define NHIST 32
#define MAXSLOT (NTOK + NRULE * 15)   // 20224
#define NTILE16 (MAXSLOT / 16)        // 1264 tiles of 16 slots

typedef __attribute__((ext_vector_type(8))) short bf16x8;
typedef __attribute__((ext_vector_type(4))) float f32x4;
typedef __attribute__((ext_vector_type(4))) short s16x4;

typedef const __attribute__((address_space(1))) unsigned int GU32;
typedef __attribute__((address_space(3))) unsigned int LU32;

#define MFMA __builtin_amdgcn_mfma_f32_16x16x32_bf16
#define SBAR() __builtin_amdgcn_sched_barrier(0)

// counted wait (rule #18: sched_barrier after, else MFMA hoists past it)
#define VMCNT(n) do { asm volatile("s_waitcnt vmcnt(" #n ")" ::: "memory"); \
                      __builtin_amdgcn_sched_barrier(0); } while (0)
// raw barrier: drain LDS counter only (hstmp visibility), NOT vmcnt
#define BARL()   do { __builtin_amdgcn_sched_barrier(0); \
                      asm volatile("s_waitcnt lgkmcnt(0)" ::: "memory"); \
                      __builtin_amdgcn_s_barrier(); \
                      __builtin_amdgcn_sched_barrier(0); } while (0)
// un-sinkable 16B register load (issue order = program order)
#define GLOAD(dst, ptr) \
    asm volatile("global_load_dwordx4 %0, %1, off" : "=v"(dst) : "v"(ptr) : "memory")

__device__ inline short f2bs(float f) {
    __hip_bfloat16 h = __float2bfloat16(f);
    return *reinterpret_cast<short*>(&h);
}
__device__ inline bf16x8 cvt8(const float4& a, const float4& b) {
    bf16x8 r;
    r[0] = f2bs(a.x); r[1] = f2bs(a.y); r[2] = f2bs(a.z); r[3] = f2bs(a.w);
    r[4] = f2bs(b.x); r[5] = f2bs(b.y); r[6] = f2bs(b.z); r[7] = f2bs(b.w);
    return r;
}

// ---------------------------------------------------------------------------
// prep A: blocks 0..127 pack weights into MFMA B-frag layout (bf16);
//         blocks 128..159 per-block histogram slabs + init perm/srid.
// ---------------------------------------------------------------------------
__global__ void kprep_a(const int* __restrict__ rule_ids,
                        const float* __restrict__ shared_in,
                        const float* __restrict__ shared_out,
                        const float* __restrict__ rule_in,
                        const float* __restrict__ rule_out,
                        unsigned short* __restrict__ ssb,   // [64k32][3nf][64][8]
                        unsigned short* __restrict__ sob,   // [128CF][2kc][64][8]
                        unsigned short* __restrict__ rinf,  // [256][2half][64][8]
                        unsigned short* __restrict__ rof,   // [256][4cf][64][8]
                        int* __restrict__ ghist_part,
                        int* __restrict__ perm_p,
                        int* __restrict__ srid_p)
{
    if (blockIdx.x < 128) {
        const int tid = blockIdx.x * 256 + threadIdx.x;
        const int stride = 128 * 256;
        for (int idx = tid; idx < 64 * 3 * 512; idx += stride) {
            int ch = idx / 1536, rem = idx - ch * 1536;
            int nf = rem / 512;
            int l = (rem >> 3) & 63, j = idx & 7;
            int k = ch * 32 + ((l >> 4) << 3) + j;
            int col = nf * 16 + (l & 15);
            ssb[idx] = (col < SR) ? (unsigned short)f2bs(shared_in[(size_t)k * SR + col]) : 0;
        }
        for (int idx = tid; idx < 128 * 2 * 512; idx += stride) {
            int CF = idx >> 10;
            int kc = (idx >> 9) & 1;
            int l = (idx >> 3) & 63, j = idx & 7;
            int k = kc * 32 + ((l >> 4) << 3) + j;
            int col = CF * 16 + (l & 15);
            sob[idx] = (k < SR) ? (unsigned short)f2bs(shared_out[(size_t)k * OUTF + col]) : 0;
        }
        for (int idx = tid; idx < NRULE * 2 * 512; idx += stride) {
            int rid = idx >> 10;
            int half = (idx >> 9) & 1;
            int l = (idx >> 3) & 63, j = idx & 7;
            int r = l & 15;
            int s = half * 32 + ((l >> 4) << 3) + j;
            rinf[idx] = (r < RANK) ? (unsigned short)f2bs(rule_in[(size_t)rid * 512 + s * RANK + r]) : 0;
        }
        for (int idx = tid; idx < NRULE * 4 * 512; idx += stride) {
            int rid = idx >> 11;
            int cf = (idx >> 9) & 3;
            int l = (idx >> 3) & 63, j = idx & 7;
            int k = ((l >> 4) << 3) + j;
            int c = cf * 16 + (l & 15);
            rof[idx] = (k < RANK) ? (unsigned short)f2bs(rule_out[(size_t)rid * 512 + k * BLK + c]) : 0;
        }
    } else {
        __shared__ int lh[NRULE];
        const int tid = threadIdx.x;
        const int hb = blockIdx.x - 128;
        lh[tid] = 0;
        __syncthreads();
        const int base = hb * 512;
        atomicAdd(&lh[rule_ids[base + tid]], 1);
        atomicAdd(&lh[rule_ids[base + 256 + tid]], 1);
        __syncthreads();
        ghist_part[hb * NRULE + tid] = lh[tid];
        for (int j = tid; j < MAXSLOT / 32; j += 256) {
            int idx = hb * (MAXSLOT / 32) + j;
            perm_p[idx] = -1;
            srid_p[idx] = 0;
        }
    }
}

__global__ void kprep_scan(const int* __restrict__ ghist_part,
                           const float* __restrict__ logits,
                           int* __restrict__ gcnt,
                           int* __restrict__ srid_p,
                           float* __restrict__ sel_t,
                           int* __restrict__ ntot)
{
    __shared__ int sc[NRULE];
    const int tid = threadIdx.x;
    int h = 0;
#pragma unroll
    for (int b = 0; b < NHIST; ++b) h += ghist_part[b * NRULE + tid];
    const int pd = (h + 15) & ~15;
    sc[tid] = pd;
    for (int off = 1; off < NRULE; off <<= 1) {
        __syncthreads();
        int v = (tid >= off) ? sc[tid - off] : 0;
        __syncthreads();
        sc[tid] += v;
    }
    __syncthreads();
    const int excl = sc[tid] - pd;
    gcnt[tid] = excl;
    for (int q = h; q < pd; ++q) srid_p[excl + q] = tid;
    if (tid == NRULE - 1) *ntot = sc[tid];
    const float invT = 5.65685424949238f;
    const float* __restrict__ lg = logits + (size_t)tid * NBLK;
    float m = -1e30f;
    for (int b = 0; b < NBLK; ++b) m = fmaxf(m, lg[b] * invT);
    float s = 0.0f;
    for (int b = 0; b < NBLK; ++b) s += expf(lg[b] * invT - m);
    const float inv = 1.0f / s;
    for (int b = 0; b < NBLK; ++b)
        sel_t[(size_t)tid * NBLK + b] = expf(lg[b] * invT - m) * inv;
}

__global__ void kprep_scatter(const int* __restrict__ rule_ids,
                              int* __restrict__ gcnt,
                              int* __restrict__ perm_p,
                              int* __restrict__ srid_p)
{
    const int i = blockIdx.x * 256 + threadIdx.x;
    const int r = rule_ids[i];
    const int p = atomicAdd(&gcnt[r], 1);
    perm_p[p] = i;
    srid_p[p] = r;
}

// ---------------------------------------------------------------------------
// kmain: 16 slots, 128 thr = 2 waves (kh = k-sub).
// Phase 1: 2-deep counted pipeline. x -> LDS ring[3] via global_load_lds,
//   staged 2 chunks ahead; weights via asm GLOAD 2 chunks ahead (2-slot reg
//   ring). ALL loop VMEM is manual -> exact vmcnt: 5 ops/iter (2 DMA + 3 W),
//   steady-state vmcnt(5). Raw s_barrier with lgkmcnt-only drain: DMA stays
//   in flight across barriers (T3/T4). XOR source swizzle as R12.
// Phase 2: unchanged from R12 (compiler-scheduled ring, predicated stores).
// LDS ~25 KB -> 6 blocks/CU (grid-bound at ~4.9 anyway).
// ---------------------------------------------------------------------------
__global__ __launch_bounds__(128, 4)
void kmain(const float* __restrict__ x,
           const int* __restrict__ perm_p,
           const int* __restrict__ srid_p,
           const unsigned short* __restrict__ ssb,
           const unsigned short* __restrict__ sob,
           const unsigned short* __restrict__ rinf,
           const unsigned short* __restrict__ rof,
           const float* __restrict__ sel_t,
           const int* __restrict__ ntot,
           float* __restrict__ out)
{
    __shared__ __align__(16) float xbuf[3][1024];             // 12 KB ring
    __shared__ __align__(16) float hstmp[2][2][16][8];        // 2 KB
    __shared__ __align__(16) unsigned short hs_lds[16][264];  // 8.25 KB
    __shared__ __align__(16) unsigned short t_bf[16][72];     // 2.25 KB
    __shared__ float sel_lds[NBLK];                           // 128 B

#define TRD(W, SL, C) (((float*)xbuf)[((W) * 16 + (SL)) * 52 + (C)])

    const int slot0 = blockIdx.x * 16;
    if (slot0 >= *ntot) return;

    const int tid  = threadIdx.x;       // 0..127
    const int lane = tid & 63;
    const int kh   = tid >> 6;          // k-sub (ph1) / col-half (ph2)
    const int row_l = lane & 15, grp = lane >> 4;

    const int rid_u = __builtin_amdgcn_readfirstlane(srid_p[slot0]);

    // staging: 16 rows x 16 units(16B); thread covers rows r0 and r0+8
    const int r0 = tid >> 4;            // 0..7
    const int u  = tid & 15;
    int tokA = perm_p[slot0 + r0];      if (tokA < 0) tokA = 0;
    int tokB = perm_p[slot0 + r0 + 8];  if (tokB < 0) tokB = 0;
    const char* gA = (const char*)(x + (size_t)tokA * INF) + ((u ^ (r0 & 7)) << 4);
    const char* gB = (const char*)(x + (size_t)tokB * INF) + ((u ^ (r0 & 7)) << 4);

#define STAGE(CH) do { \
        char* _lb = (char*)xbuf + (size_t)((CH) % 3) * 4096 + (kh << 10); \
        const size_t _o = (size_t)(CH) << 8; \
        __builtin_amdgcn_global_load_lds((GU32*)(gA + _o), (LU32*)_lb,          16, 0, 0); \
        __builtin_amdgcn_global_load_lds((GU32*)(gB + _o), (LU32*)(_lb + 2048), 16, 0, 0); \
    } while (0)

#define WLOAD(SLOT, CH) do { \
        const unsigned short* _wp = ssb + (size_t)((CH) * 2 + kh) * 1536 + lane * 8; \
        GLOAD(wreg[SLOT][0], _wp); \
        GLOAD(wreg[SLOT][1], _wp + 512); \
        GLOAD(wreg[SLOT][2], _wp + 1024); \
    } while (0)

    // ds_read offsets (XOR-swizzled) for this wave's fragment
    const int offA = (row_l * 16 + ((kh * 8 + grp * 2 + 0) ^ (row_l & 7))) << 4;
    const int offB = (row_l * 16 + ((kh * 8 + grp * 2 + 1) ^ (row_l & 7))) << 4;

    const bf16x8 ri = *(const bf16x8*)(rinf + ((size_t)rid_u * 2 + kh) * 512 + lane * 8);
    if (tid < NBLK) sel_lds[tid] = sel_t[(size_t)rid_u * NBLK + tid];

    f32x4 aT0 = {0.f, 0.f, 0.f, 0.f};
    f32x4 aT1 = {0.f, 0.f, 0.f, 0.f};
    f32x4 aT2 = {0.f, 0.f, 0.f, 0.f};
    bf16x8 wreg[2][3];

    __syncthreads();        // drain everything: counting starts clean here

    // prologue issue log (per wave): D0 D0 W0 W0 W0 D1 D1 W1 W1 W1  (10)
    STAGE(0); WLOAD(0, 0);
    STAGE(1); WLOAD(1, 1);

#pragma unroll
    for (int ch = 0; ch < 32; ++ch) {
        // wait: chunk ch's 5 ops landed; next chunk's 5 stay in flight
        if (ch < 31) VMCNT(5); else VMCNT(0);
        BARL();                            // both waves' DMA(ch) visible
        if (ch < 30) STAGE(ch + 2);        // overwrites buf[(ch-1)%3]: safe
        // finish hidden of previous chunk (hstmp written before last BARL)
        if (ch > 0) {
            const int b = ch - 1, pb = b & 1;
            const int sl = tid >> 3, r = tid & 7;
            const float v = hstmp[pb][0][sl][r] + hstmp[pb][1][sl][r];
            hs_lds[sl][b * 8 + r] = (unsigned short)f2bs(v * sel_lds[b]);
        }
        // compute sub kh of chunk ch
        {
            const char* xb = (const char*)xbuf + (size_t)(ch % 3) * 4096;
            const float4 fa = *(const float4*)(xb + offA);
            const float4 fb = *(const float4*)(xb + offB);
            const bf16x8 af = cvt8(fa, fb);
            f32x4 aH = {0.f, 0.f, 0.f, 0.f};
            aT0 = MFMA(af, wreg[ch & 1][0], aT0, 0, 0, 0);
            aT1 = MFMA(af, wreg[ch & 1][1], aT1, 0, 0, 0);
            aT2 = MFMA(af, wreg[ch & 1][2], aT2, 0, 0, 0);
            aH  = MFMA(af, ri, aH, 0, 0, 0);
            if (row_l < RANK) {
#pragma unroll
                for (int q = 0; q < 4; ++q)
                    hstmp[ch & 1][kh][(grp << 2) + q][row_l] = aH[q];
            }
        }
        if (ch < 30) WLOAD(ch & 1, ch + 2); // after compute consumed the slot
    }
    __syncthreads();

    // ---- epilogue: hidden for chunk 31; t partials -> tred (xbuf overlay) --
    {
        const int b = 31, pb = 1;
        const int sl = tid >> 3, r = tid & 7;
        const float v = hstmp[pb][0][sl][r] + hstmp[pb][1][sl][r];
        hs_lds[sl][b * 8 + r] = (unsigned short)f2bs(v * sel_lds[b]);
    }
#pragma unroll
    for (int q = 0; q < 4; ++q) {
        const int sl = (grp << 2) + q;
        TRD(kh, sl, row_l)      = aT0[q];
        TRD(kh, sl, 16 + row_l) = aT1[q];
        TRD(kh, sl, 32 + row_l) = aT2[q];
    }
    __syncthreads();
    {   // reduce the 2 k-subs -> bf16 t (16 slots x 64 cols, K-padded)
        const int sl = tid >> 3;         // 0..15
        const int cidx = tid & 7;
        if (cidx < 6) {
            const int c0 = cidx << 3;
            s16x4 v0, v1;
#pragma unroll
            for (int j = 0; j < 4; ++j) {
                v0[j] = f2bs(TRD(0, sl, c0 + j)     + TRD(1, sl, c0 + j));
                v1[j] = f2bs(TRD(0, sl, c0 + 4 + j) + TRD(1, sl, c0 + 4 + j));
            }
            *(s16x4*)(&t_bf[sl][c0])     = v0;
            *(s16x4*)(&t_bf[sl][c0 + 4]) = v1;
        } else {
            const int c0 = 48 + ((cidx - 6) << 3);
            const s16x4 z = {0, 0, 0, 0};
            *(s16x4*)(&t_bf[sl][c0])     = z;
            *(s16x4*)(&t_bf[sl][c0 + 4]) = z;
        }
    }
    __syncthreads();

    // ================= phase 2: out = t@shared_out + hs@rule_out ===========
    {
        const int p = kh;                // col-half: [p*1024, +1024)
        const bf16x8 at0 = *(const bf16x8*)(&t_bf[row_l][grp << 3]);
        const bf16x8 at1 = *(const bf16x8*)(&t_bf[row_l][32 + (grp << 3)]);

        bf16x8 rfv[4];
#pragma unroll
        for (int i = 0; i < 4; ++i)
            rfv[i] = *(const bf16x8*)(rof + ((size_t)rid_u * 4 + i) * 512 + lane * 8);

        const int4 pv = *(const int4*)(perm_p + slot0 + (grp << 2));
        float* const orow0 = out + (size_t)(pv.x < 0 ? 0 : pv.x) * OUTF;
        float* const orow1 = out + (size_t)(pv.y < 0 ? 0 : pv.y) * OUTF;
        float* const orow2 = out + (size_t)(pv.z < 0 ? 0 : pv.z) * OUTF;
        float* const orow3 = out + (size_t)(pv.w < 0 ? 0 : pv.w) * OUTF;

        const int CF0 = p * 64;
        const int bb0 = p * 16;
        const unsigned short* __restrict__ sobw = sob + (size_t)CF0 * 1024 + lane * 8;

        bf16x8 sb[4][2];
        bf16x8 ah[2];
        const bf16x8 zz = {0, 0, 0, 0, 0, 0, 0, 0};

#define LOADQ(SL, QI) do { \
        const unsigned short* _sp = sobw + (size_t)(QI) * 1024; \
        sb[SL][0] = *(const bf16x8*)(_sp); \
        sb[SL][1] = *(const bf16x8*)(_sp + 512); \
    } while (0)
#define LOADA(SL, BI) do { \
        ah[SL] = zz; \
        if (lane < 16) \
            ah[SL] = *(const bf16x8*)(&hs_lds[lane][(bb0 + (BI)) * 8]); \
    } while (0)

        LOADQ(0, 0); LOADQ(1, 1); LOADQ(2, 2);
        LOADA(0, 0);
        SBAR();

#pragma unroll
        for (int qi = 0; qi < 64; ++qi) {
            if (qi < 61) LOADQ((qi + 3) & 3, qi + 3);
            if ((qi & 3) == 0 && qi < 60) LOADA(((qi >> 2) + 1) & 1, (qi >> 2) + 1);
            SBAR();
            f32x4 acc = {0.f, 0.f, 0.f, 0.f};
            acc = MFMA(at0, sb[qi & 3][0], acc, 0, 0, 0);
            acc = MFMA(at1, sb[qi & 3][1], acc, 0, 0, 0);
            acc = MFMA(ah[(qi >> 2) & 1], rfv[qi & 3], acc, 0, 0, 0);
            const int col = ((CF0 + qi) << 4) + row_l;
            if (pv.x >= 0) orow0[col] = acc[0];
            if (pv.y >= 0) orow1[col] = acc[1];
            if (pv.z >= 0) orow2[col] = acc[2];
            if (pv.w >= 0) orow3[col] = acc[3];
            SBAR();
        }
#undef LOADQ
#undef LOADA
    }
}

extern "C" void kernel_launch(void* const* d_in, const int* in_sizes, int n_in,
                              void* d_out, int out_size, void* d_ws, size_t ws_size,
                              hipStream_t stream)
{
    const float* x          = (const float*)d_in[0];
    const int*   rule_ids   = (const int*)  d_in[1];
    const float* shared_in  = (const float*)d_in[2];
    const float* shared_out = (const float*)d_in[3];
    const float* rule_in    = (const float*)d_in[4];
    const float* rule_out   = (const float*)d_in[5];
    const float* logits     = (const float*)d_in[6];
    float* out = (float*)d_out;

    char* p = (char*)d_ws;
    auto carve = [&p](size_t bytes) {
        char* r = p;
        p += (bytes + 255) & ~(size_t)255;
        return r;
    };
    int*            perm_p = (int*)carve(MAXSLOT * 4);
    int*            srid_p = (int*)carve(MAXSLOT * 4);
    unsigned short* ssb    = (unsigned short*)carve(64 * 3 * 512 * 2);
    unsigned short* sob    = (unsigned short*)carve(128 * 2 * 512 * 2);
    unsigned short* rinf   = (unsigned short*)carve((size_t)NRULE * 2 * 512 * 2);
    unsigned short* rof    = (unsigned short*)carve((size_t)NRULE * 4 * 512 * 2);
    float*          sel_t  = (float*)carve((size_t)NRULE * NBLK * 4);
    int*            ghistp = (int*)carve((size_t)NHIST * NRULE * 4);
    int*            gcnt   = (int*)carve(NRULE * 4);
    int*            ntot   = (int*)carve(4);

    kprep_a<<<dim3(160), dim3(256), 0, stream>>>(
        rule_ids, shared_in, shared_out, rule_in, rule_out,
        ssb, sob, rinf, rof, ghistp, perm_p, srid_p);
    kprep_scan<<<dim3(1), dim3(256), 0, stream>>>(
        ghistp, logits, gcnt, srid_p, sel_t, ntot);
    kprep_scatter<<<dim3(64), dim3(256), 0, stream>>>(
        rule_ids, gcnt, perm_p, srid_p);
    kmain<<<dim3(NTILE16), dim3(128), 0, stream>>>(
        x, perm_p, srid_p, ssb, sob, rinf, rof, sel_t, ntot, out);
}